// Round 5
// baseline (857.540 us; speedup 1.0000x reference)
//
#include <hip/hip_runtime.h>
#include <hip/hip_bf16.h>
#include <math.h>
#include <stdint.h>

#define TTOK 25088
#define NTOK 196

typedef __bf16 bf16x8_t __attribute__((ext_vector_type(8)));
typedef float f32x4_t __attribute__((ext_vector_type(4)));
typedef __hip_bfloat16 bf16;

__device__ __forceinline__ void async16(void* lds, const void* g) {
  __builtin_amdgcn_global_load_lds((const __attribute__((address_space(1))) unsigned int*)g,
                                   (__attribute__((address_space(3))) unsigned int*)lds, 16, 0, 0);
}

// fast GELU: x * sigmoid(1.5957691(x + 0.044715 x^3))  (== tanh-form GELU)
__device__ __forceinline__ float gelu_f(float x) {
  float u = x * (1.5957691216057308f + 0.07135481627f * x * x);
  return x / (1.0f + __expf(-u));
}

__device__ __forceinline__ bf16x8_t zero_bf16x8() {
  bf16x8_t v;
#pragma unroll
  for (int i = 0; i < 8; i++) v[i] = (__bf16)0.0f;
  return v;
}

// ---------------- generic token-major GEMM: out[t][co] = sum_k X[t][k]*W[co][k] ----------------
// EPI: 0 = +bias ; 1 = +bias,gelu ; 2 = +bias,+residual ; 3 = +bias,+residual, f32 out in [b][c][n] layout
// MT: M-tile (128 -> 256 threads, 64 -> 128 threads; N-tile fixed 128)
template<int K, int EPI, int MT>
__global__ __launch_bounds__(MT * 2) void gemm_bt(
    const bf16* __restrict__ X, const bf16* __restrict__ W,
    const float* __restrict__ bias, const bf16* __restrict__ res,
    bf16* __restrict__ out, float* __restrict__ outf, int Co)
{
  __shared__ __align__(16) bf16 As[MT * 32];
  __shared__ __align__(16) bf16 Bs[128 * 32];
  constexpr int T = MT * 2;
  const int tid = threadIdx.x;
  const int lane = tid & 63;
  const int wv = tid >> 6;
  const int quad = lane >> 4, l15 = lane & 15;
  const int wm = (MT == 128) ? (wv >> 1) : 0;
  const int wn = (MT == 128) ? (wv & 1) : wv;
  const int t0 = blockIdx.x * MT;
  const int n0 = blockIdx.y * 128;

  f32x4_t acc[4][4];
#pragma unroll
  for (int i = 0; i < 4; i++)
#pragma unroll
    for (int j = 0; j < 4; j++) {
      acc[i][j][0] = 0.f; acc[i][j][1] = 0.f; acc[i][j][2] = 0.f; acc[i][j][3] = 0.f;
    }

  constexpr int KT = K / 32;
  for (int kk = 0; kk < KT; kk++) {
    if (kk) __syncthreads();
#pragma unroll
    for (int ch = tid; ch < MT * 4; ch += T) {     // A: MT rows x 32 cols, 16B chunks
      int row = ch >> 2;
      int colb = (ch & 3) << 4;
      async16((char*)As + ch * 16,
              (const char*)X + ((size_t)(t0 + row) * K + kk * 32) * 2 + colb);
    }
#pragma unroll
    for (int ch = tid; ch < 512; ch += T) {        // B: 128 rows x 32 cols
      int row = ch >> 2;
      int colb = (ch & 3) << 4;
      async16((char*)Bs + ch * 16,
              (const char*)W + ((size_t)(n0 + row) * K + kk * 32) * 2 + colb);
    }
    __syncthreads();
    bf16x8_t a[4], b[4];
#pragma unroll
    for (int mt = 0; mt < 4; mt++)
      a[mt] = *(const bf16x8_t*)(As + (wm * 64 + mt * 16 + l15) * 32 + quad * 8);
#pragma unroll
    for (int nt = 0; nt < 4; nt++)
      b[nt] = *(const bf16x8_t*)(Bs + (wn * 64 + nt * 16 + l15) * 32 + quad * 8);
#pragma unroll
    for (int mt = 0; mt < 4; mt++)
#pragma unroll
      for (int nt = 0; nt < 4; nt++)
        acc[mt][nt] = __builtin_amdgcn_mfma_f32_16x16x32_bf16(a[mt], b[nt], acc[mt][nt], 0, 0, 0);
  }

#pragma unroll
  for (int nt = 0; nt < 4; nt++) {
    int co = n0 + wn * 64 + nt * 16 + l15;
    float bv = bias[co];
#pragma unroll
    for (int mt = 0; mt < 4; mt++) {
#pragma unroll
      for (int r = 0; r < 4; r++) {
        int t = t0 + wm * 64 + mt * 16 + quad * 4 + r;
        float v = acc[mt][nt][r] + bv;
        if constexpr (EPI == 1) v = gelu_f(v);
        if constexpr (EPI >= 2) v += (float)res[(size_t)t * Co + co];
        if constexpr (EPI == 3) {
          int bb = t / NTOK, nsp = t % NTOK;
          outf[((size_t)bb * 384 + co) * NTOK + nsp] = v;
        } else {
          out[(size_t)t * Co + co] = bf16(v);
        }
      }
    }
  }
}

// ---------------- attention: one block per (b,h); chunked P (LDS 43KB -> 3 blocks/CU) ----------------
__global__ __launch_bounds__(256) void attn_kernel(
    const bf16* __restrict__ q, int sq,
    const bf16* __restrict__ kv, int skv, int kofs0, int vofs0,
    const float* __restrict__ bmat, bf16* __restrict__ outp)
{
  __shared__ __align__(16) bf16 Ks[196 * 48];
  __shared__ __align__(16) bf16 VT[48 * 208];
  __shared__ __align__(16) bf16 Pc[4][16 * 32];
  const int b = blockIdx.x >> 3, h = blockIdx.x & 7;
  const int tid = threadIdx.x;
  const int lane = tid & 63, wv = tid >> 6;
  const int quad = lane >> 4, l15 = lane & 15;
  const int qoff = h * 48, koff = kofs0 + h * 48, voff = vofs0 + h * 48;
  const float SC = 0.14433756729740643f;  // 48^-0.5

  for (int j = 0; j < 5; j++) {
    int idx = j * 256 + tid;
    if (idx < 1176) {
      int o = idx * 16;
      int row = o / 96, colb = o % 96;
      async16((char*)Ks + o,
              (const char*)kv + ((size_t)(b * 196 + row) * skv + koff) * 2 + colb);
    }
  }
  for (int i = tid; i < 196 * 48; i += 256) {
    int mk = i / 48, d = i % 48;
    VT[d * 208 + mk] = kv[(size_t)(b * 196 + mk) * skv + voff + d];
  }
  for (int i = tid; i < 48 * 12; i += 256) {
    int d = i / 12, mk = 196 + (i % 12);
    VT[d * 208 + mk] = bf16(0.0f);
  }
  __syncthreads();

  for (int qt = wv; qt < 13; qt += 4) {
    int trow = qt * 16 + l15;
    int tl = trow < 196 ? trow : 195;
    const bf16* qrow = q + (size_t)(b * 196 + tl) * sq + qoff;
    bf16x8_t aq0 = *(const bf16x8_t*)(qrow + quad * 8);
    bf16x8_t aq1 = zero_bf16x8();
    if (quad < 2) aq1 = *(const bf16x8_t*)(qrow + 32 + quad * 8);

    f32x4_t S[13];
#pragma unroll
    for (int kt = 0; kt < 13; kt++) { S[kt][0] = 0.f; S[kt][1] = 0.f; S[kt][2] = 0.f; S[kt][3] = 0.f; }

#pragma unroll
    for (int kt = 0; kt < 13; kt++) {
      int kr = kt * 16 + l15;
      bf16x8_t bk0 = zero_bf16x8(), bk1 = zero_bf16x8();
      if (kr < 196) {
        const bf16* krow = Ks + kr * 48;
        bk0 = *(const bf16x8_t*)(krow + quad * 8);
        if (quad < 2) bk1 = *(const bf16x8_t*)(krow + 32 + quad * 8);
      }
      S[kt] = __builtin_amdgcn_mfma_f32_16x16x32_bf16(aq0, bk0, S[kt], 0, 0, 0);
      S[kt] = __builtin_amdgcn_mfma_f32_16x16x32_bf16(aq1, bk1, S[kt], 0, 0, 0);
    }

    float mrow[4] = {-1e30f, -1e30f, -1e30f, -1e30f};
#pragma unroll
    for (int kt = 0; kt < 13; kt++) {
      int m = kt * 16 + l15;
      int mc = m < 196 ? m : 195;
#pragma unroll
      for (int r = 0; r < 4; r++) {
        int qg = qt * 16 + quad * 4 + r;
        int qc = qg < 196 ? qg : 195;
        float s = S[kt][r] * SC + bmat[((size_t)h * 196 + qc) * 196 + mc];
        if (m >= 196) s = -1e30f;
        S[kt][r] = s;
        mrow[r] = fmaxf(mrow[r], s);
      }
    }
#pragma unroll
    for (int r = 0; r < 4; r++)
#pragma unroll
      for (int off = 1; off < 16; off <<= 1)
        mrow[r] = fmaxf(mrow[r], __shfl_xor(mrow[r], off));
    float srow[4] = {0.f, 0.f, 0.f, 0.f};
#pragma unroll
    for (int kt = 0; kt < 13; kt++)
#pragma unroll
      for (int r = 0; r < 4; r++) {
        float p = __expf(S[kt][r] - mrow[r]);
        S[kt][r] = p;
        srow[r] += p;
      }
#pragma unroll
    for (int r = 0; r < 4; r++) {
#pragma unroll
      for (int off = 1; off < 16; off <<= 1)
        srow[r] += __shfl_xor(srow[r], off);
      srow[r] = 1.0f / srow[r];
    }

    // P @ V with per-wave 16x32 chunked P round-trip (C-layout -> A-layout)
    f32x4_t O[3];
#pragma unroll
    for (int dt = 0; dt < 3; dt++) { O[dt][0] = 0.f; O[dt][1] = 0.f; O[dt][2] = 0.f; O[dt][3] = 0.f; }
#pragma unroll
    for (int ks = 0; ks < 7; ks++) {
#pragma unroll
      for (int half = 0; half < 2; half++) {
        int kt = ks * 2 + half;
#pragma unroll
        for (int r = 0; r < 4; r++) {
          float pv = (kt < 13) ? S[kt][r] * srow[r] : 0.f;
          Pc[wv][(quad * 4 + r) * 32 + half * 16 + l15] = bf16(pv);
        }
      }
      bf16x8_t ap = *(const bf16x8_t*)(&Pc[wv][l15 * 32 + quad * 8]);
#pragma unroll
      for (int dt = 0; dt < 3; dt++) {
        bf16x8_t bv8 = zero_bf16x8();
        if (ks < 6 || quad < 2)
          bv8 = *(const bf16x8_t*)(VT + (dt * 16 + l15) * 208 + ks * 32 + quad * 8);
        O[dt] = __builtin_amdgcn_mfma_f32_16x16x32_bf16(ap, bv8, O[dt], 0, 0, 0);
      }
    }
#pragma unroll
    for (int dt = 0; dt < 3; dt++)
#pragma unroll
      for (int r = 0; r < 4; r++) {
        int tq = qt * 16 + quad * 4 + r;
        if (tq < 196)
          outp[(size_t)(b * 196 + tq) * 384 + qoff + dt * 16 + l15] = bf16(O[dt][r]);
      }
  }
}

// ---------------- RepVGGDW (dw3x3 + dw1x1 + id) + GELU -> token-major bf16 ----------------
// v4: no LDS — direct global reads with a sliding 3-row register window.
// thread = (channel c, 4-row band). Rows re-read by neighbor bands hit L2.
__device__ __forceinline__ void load_row14(float* d, const float* rowp, bool valid) {
  if (valid) {
    const float2* p2 = (const float2*)rowp;
#pragma unroll
    for (int j = 0; j < 7; j++) { float2 v = p2[j]; d[2 * j] = v.x; d[2 * j + 1] = v.y; }
  } else {
#pragma unroll
    for (int w = 0; w < 14; w++) d[w] = 0.f;
  }
}

__global__ __launch_bounds__(256) void conv_kernel(
    const float* __restrict__ lh, const float* __restrict__ hl, const float* __restrict__ hh,
    const float* __restrict__ w3, const float* __restrict__ b3,
    const float* __restrict__ w1, const float* __restrict__ b1,
    bf16* __restrict__ outp)
{
  const int tid = threadIdx.x;
  const int b = blockIdx.x / 18, chunk = blockIdx.x % 18;
  const int c0 = chunk * 64;
  const float* src = (c0 < 384) ? lh : (c0 < 768 ? hl : hh);
  const int cc0 = c0 % 384;
  const int c = tid & 63;
  const int g = tid >> 6;               // band: rows 4g .. min(4g+3,13)
  const int cg = c0 + c;
  const float* base = src + ((size_t)b * 384 + cc0 + c) * 196;

  float w9[9];
#pragma unroll
  for (int k = 0; k < 9; k++) w9[k] = w3[cg * 9 + k];
  w9[4] += w1[cg] + 1.0f;               // fold dw1x1 + identity into center tap
  const float bb = b3[cg] + b1[cg];

  const int r0 = 4 * g;
  float rows[3][14];
  load_row14(rows[0], base + (r0 - 1) * 14, r0 - 1 >= 0);
  load_row14(rows[1], base + r0 * 14, true);

#pragma unroll
  for (int s = 0; s < 4; s++) {
    int r = r0 + s;
    if (r < 14) {
      float* rp = rows[(s + 2) % 3];
      load_row14(rp, base + (r + 1) * 14, r + 1 < 14);
      const float* rm = rows[s % 3];
      const float* rc = rows[(s + 1) % 3];
      bf16* orow = outp + ((size_t)b * 196 + r * 14) * 1152 + cg;
#pragma unroll
      for (int w = 0; w < 14; w++) {
        float ss = bb + rm[w] * w9[1] + rc[w] * w9[4] + rp[w] * w9[7];
        if (w > 0)  ss += rm[w - 1] * w9[0] + rc[w - 1] * w9[3] + rp[w - 1] * w9[6];
        if (w < 13) ss += rm[w + 1] * w9[2] + rc[w + 1] * w9[5] + rp[w + 1] * w9[8];
        orow[(size_t)w * 1152] = bf16(gelu_f(ss));
      }
    }
  }
}

// ---------------- SE: pool -> (scale matvec + apply fused) ----------------
__global__ __launch_bounds__(256) void pool_kernel(
    const float* __restrict__ ll, float* __restrict__ pooled)
{
  const int b = blockIdx.x / 6, chunk = blockIdx.x % 6;
  const int c0 = chunk * 64;
  const int wv = threadIdx.x >> 6, lane = threadIdx.x & 63;
  for (int c = wv; c < 64; c += 4) {
    const float* p = ll + ((size_t)b * 384 + c0 + c) * 196;
    float v = p[lane] + p[64 + lane] + p[128 + lane] + (lane < 4 ? p[192 + lane] : 0.f);
#pragma unroll
    for (int off = 32; off; off >>= 1) v += __shfl_xor(v, off);
    if (lane == 0) pooled[b * 384 + c0 + c] = v * (1.0f / 196.0f);
  }
}

__global__ __launch_bounds__(256) void seapply_kernel(
    const float* __restrict__ ll, const float* __restrict__ pooled,
    const float* __restrict__ ew, const float* __restrict__ eb,
    bf16* __restrict__ se)
{
  __shared__ float pl[384];
  __shared__ float scale[64];
  __shared__ float plane[64][197];
  const int tid = threadIdx.x;
  const int b = blockIdx.x / 6, chunk = blockIdx.x % 6;
  const int c0 = chunk * 64;
  const int wv = tid >> 6, lane = tid & 63;

  for (int i = tid; i < 384; i += 256) pl[i] = pooled[b * 384 + i];
  for (int i = tid; i < 64 * 196; i += 256) {
    int c = i / 196, n = i % 196;
    plane[c][n] = ll[((size_t)b * 384 + c0 + c) * 196 + n];
  }
  __syncthreads();
  for (int cc = wv; cc < 64; cc += 4) {
    const float* wr = ew + (size_t)(c0 + cc) * 384;
    float v = 0.f;
#pragma unroll
    for (int j = 0; j < 6; j++) v += wr[j * 64 + lane] * pl[j * 64 + lane];
#pragma unroll
    for (int off = 32; off; off >>= 1) v += __shfl_xor(v, off);
    if (lane == 0) {
      float y = (v + eb[c0 + cc]) * (1.0f / 6.0f) + 0.5f;
      scale[cc] = fminf(fmaxf(y, 0.f), 1.f);
    }
  }
  __syncthreads();
  const int c = tid & 63;
  const float sc = scale[c];
  for (int n = tid >> 6; n < 196; n += 4)
    se[((size_t)b * 196 + n) * 384 + c0 + c] = bf16(plane[c][n] * sc);
}

// ---------------- prep: weight f32->bf16 blob + bias-table materialize (merged) ----------------
__global__ __launch_bounds__(256) void prep_kernel(
    const float* p0, const float* p1, const float* p2, const float* p3, const float* p4,
    const float* p5, const float* p6, const float* p7, const float* p8, const float* p9,
    bf16* dst,
    const float* __restrict__ hbias, const float* __restrict__ lbias,
    const int* __restrict__ idx, float* __restrict__ bh, float* __restrict__ bl)
{
  const int bid = blockIdx.x;
  if (bid < 10944) {
    int i = bid * 256 + threadIdx.x;   // < 2801664 always
    const int offs[11] = {0, 442368, 884736, 1032192, 1327104, 1622016,
                          1769472, 2064384, 2211840, 2506752, 2801664};
    const float* ps[10] = {p0, p1, p2, p3, p4, p5, p6, p7, p8, p9};
    int seg = 0;
#pragma unroll
    for (int k = 1; k < 10; k++) if (i >= offs[k]) seg = k;
    dst[i] = bf16(ps[seg][i - offs[seg]]);
  } else {
    int i = (bid - 10944) * 256 + threadIdx.x;
    if (i >= 307328) return;  // 8 * 196 * 196
    int h = i / 38416;
    int nm = i % 38416;
    int id = idx[nm];
    bh[i] = hbias[h * 196 + id];
    bl[i] = lbias[h * 196 + id];
  }
}

extern "C" void kernel_launch(void* const* d_in, const int* in_sizes, int n_in,
                              void* d_out, int out_size, void* d_ws, size_t ws_size,
                              hipStream_t stream) {
  const float* ll     = (const float*)d_in[0];
  const float* lh     = (const float*)d_in[1];
  const float* hl     = (const float*)d_in[2];
  const float* hh     = (const float*)d_in[3];
  const float* dw3_w  = (const float*)d_in[4];
  const float* dw3_b  = (const float*)d_in[5];
  const float* dw1_w  = (const float*)d_in[6];
  const float* dw1_b  = (const float*)d_in[7];
  const float* pw_w   = (const float*)d_in[8];
  const float* pw_b   = (const float*)d_in[9];
  const float* hqkv_w = (const float*)d_in[10];
  const float* hqkv_b = (const float*)d_in[11];
  const float* hproj_w= (const float*)d_in[12];
  const float* hproj_b= (const float*)d_in[13];
  const float* hbias  = (const float*)d_in[14];
  const float* hm1_w  = (const float*)d_in[15];
  const float* hm1_b  = (const float*)d_in[16];
  const float* hm2_w  = (const float*)d_in[17];
  const float* hm2_b  = (const float*)d_in[18];
  const float* ese_w  = (const float*)d_in[19];
  const float* ese_b  = (const float*)d_in[20];
  const float* lq_w   = (const float*)d_in[21];
  const float* lq_b   = (const float*)d_in[22];
  const float* lkv_w  = (const float*)d_in[23];
  const float* lkv_b  = (const float*)d_in[24];
  const float* lproj_w= (const float*)d_in[25];
  const float* lproj_b= (const float*)d_in[26];
  const float* lbias  = (const float*)d_in[27];
  const float* lm1_w  = (const float*)d_in[28];
  const float* lm1_b  = (const float*)d_in[29];
  const float* lm2_w  = (const float*)d_in[30];
  const float* lm2_b  = (const float*)d_in[31];
  const int* bias_idx = (const int*)d_in[32];

  char* ws = (char*)d_ws;
  bf16*  WB = (bf16*)(ws);                    // 2801664 bf16 weights
  float* BH = (float*)(ws + 5603328);         // 8x196x196 f32
  float* BL = (float*)(ws + 6832640);
  bf16*  A  = (bf16*)(ws + 8061952);          // [T][1152]
  bf16*  B1 = (bf16*)(ws + 65864704);         // [T][384]
  bf16*  B2 = (bf16*)(ws + 85132288);         // [T][384]
  bf16*  B3 = (bf16*)(ws + 104399872);        // [T][384]
  bf16*  B4 = (bf16*)(ws + 123667456);        // [T][768]
  bf16*  E  = (bf16*)(ws + 162202624);        // [T][384] (se)
  float* PO = (float*)(ws + 181470208);       // pooled [128][384]
  float* OUT = (float*)d_out;

  prep_kernel<<<12145, 256, 0, stream>>>(pw_w, hqkv_w, hproj_w, hm1_w, hm2_w,
                                         lq_w, lkv_w, lproj_w, lm1_w, lm2_w, WB,
                                         hbias, lbias, bias_idx, BH, BL);
  conv_kernel<<<2304, 256, 0, stream>>>(lh, hl, hh, dw3_w, dw3_b, dw1_w, dw1_b, A);
  pool_kernel<<<768, 256, 0, stream>>>(ll, PO);
  seapply_kernel<<<768, 256, 0, stream>>>(ll, PO, ese_w, ese_b, E);

  // high branch
  gemm_bt<1152, 0, 64><<<dim3(392, 3), 128, 0, stream>>>(A, WB + 0, pw_b, nullptr, B1, nullptr, 384);         // hc
  gemm_bt<384, 0, 128><<<dim3(196, 9), 256, 0, stream>>>(B1, WB + 442368, hqkv_b, nullptr, A, nullptr, 1152); // qkv
  attn_kernel<<<1024, 256, 0, stream>>>(A, 1152, A, 1152, 384, 768, BH, B2);                                   // attn
  gemm_bt<384, 2, 64><<<dim3(392, 3), 128, 0, stream>>>(B2, WB + 884736, hproj_b, B1, B3, nullptr, 384);      // hao
  gemm_bt<384, 1, 128><<<dim3(196, 6), 256, 0, stream>>>(B3, WB + 1032192, hm1_b, nullptr, B4, nullptr, 768); // ffn1
  gemm_bt<768, 2, 64><<<dim3(392, 3), 128, 0, stream>>>(B4, WB + 1327104, hm2_b, B3, B1, nullptr, 384);       // refined

  // low branch
  gemm_bt<384, 0, 128><<<dim3(196, 6), 256, 0, stream>>>(B1, WB + 1769472, lkv_b, nullptr, B4, nullptr, 768); // lkv
  gemm_bt<384, 0, 64><<<dim3(392, 3), 128, 0, stream>>>(E, WB + 1622016, lq_b, nullptr, B2, nullptr, 384);    // lq
  attn_kernel<<<1024, 256, 0, stream>>>(B2, 384, B4, 768, 0, 384, BL, B1);                                     // low attn
  gemm_bt<384, 2, 64><<<dim3(392, 3), 128, 0, stream>>>(B1, WB + 2064384, lproj_b, E, B3, nullptr, 384);      // ll_attn
  gemm_bt<384, 1, 128><<<dim3(196, 6), 256, 0, stream>>>(B3, WB + 2211840, lm1_b, nullptr, A, nullptr, 768);  // ffn1
  gemm_bt<768, 3, 64><<<dim3(392, 3), 128, 0, stream>>>(A, WB + 2506752, lm2_b, B3, nullptr, OUT, 384);       // output
}

// Round 6
// 754.226 us; speedup vs baseline: 1.1370x; 1.1370x over previous
//
#include <hip/hip_runtime.h>
#include <hip/hip_bf16.h>
#include <math.h>
#include <stdint.h>

#define TTOK 25088
#define NTOK 196

typedef __bf16 bf16x8_t __attribute__((ext_vector_type(8)));
typedef float f32x4_t __attribute__((ext_vector_type(4)));
typedef __hip_bfloat16 bf16;

__device__ __forceinline__ void async16(void* lds, const void* g) {
  __builtin_amdgcn_global_load_lds((const __attribute__((address_space(1))) unsigned int*)g,
                                   (__attribute__((address_space(3))) unsigned int*)lds, 16, 0, 0);
}

// fast GELU: x * sigmoid(1.5957691(x + 0.044715 x^3))  (== tanh-form GELU)
__device__ __forceinline__ float gelu_f(float x) {
  float u = x * (1.5957691216057308f + 0.07135481627f * x * x);
  return x / (1.0f + __expf(-u));
}

__device__ __forceinline__ bf16x8_t zero_bf16x8() {
  bf16x8_t v;
#pragma unroll
  for (int i = 0; i < 8; i++) v[i] = (__bf16)0.0f;
  return v;
}

// ---------------- generic token-major GEMM: out[t][co] = sum_k X[t][k]*W[co][k] ----------------
// BK=64 K-tiles (half the barrier drains vs BK=32) + XOR-swizzled LDS so ds_read_b128 is
// conflict-free (global_load_lds forces dest=base+lane*16, so the swizzle is applied to the
// global SOURCE chunk; fragment reads apply the same XOR).
// EPI: 0 = +bias ; 1 = +bias,gelu ; 2 = +bias,+residual ; 3 = +bias,+residual, f32 out [b][c][n]
// MT: M-tile (128 -> 256 threads, 64 -> 128 threads; N-tile fixed 128)
template<int K, int EPI, int MT>
__global__ __launch_bounds__(MT * 2) void gemm_bt(
    const bf16* __restrict__ X, const bf16* __restrict__ W,
    const float* __restrict__ bias, const bf16* __restrict__ res,
    bf16* __restrict__ out, float* __restrict__ outf, int Co)
{
  __shared__ __align__(16) bf16 As[MT * 64];
  __shared__ __align__(16) bf16 Bs[128 * 64];
  constexpr int T = MT * 2;
  const int tid = threadIdx.x;
  const int lane = tid & 63;
  const int wv = tid >> 6;
  const int quad = lane >> 4, l15 = lane & 15;
  const int wm = (MT == 128) ? (wv >> 1) : 0;
  const int wn = (MT == 128) ? (wv & 1) : wv;
  const int t0 = blockIdx.x * MT;
  const int n0 = blockIdx.y * 128;

  f32x4_t acc[4][4];
#pragma unroll
  for (int i = 0; i < 4; i++)
#pragma unroll
    for (int j = 0; j < 4; j++) {
      acc[i][j][0] = 0.f; acc[i][j][1] = 0.f; acc[i][j][2] = 0.f; acc[i][j][3] = 0.f;
    }

  constexpr int KT = K / 64;
  for (int kk = 0; kk < KT; kk++) {
    if (kk) __syncthreads();
    // A: MT rows x 64 cols -> 8 x 16B chunks per row, source-swizzled by row&7
#pragma unroll
    for (int ch = tid; ch < MT * 8; ch += T) {
      int row = ch >> 3;
      int sc = (ch & 7) ^ (row & 7);
      async16((char*)As + ch * 16,
              (const char*)X + ((size_t)(t0 + row) * K + kk * 64 + sc * 8) * 2);
    }
#pragma unroll
    for (int ch = tid; ch < 1024; ch += T) {       // B: 128 rows x 64 cols
      int row = ch >> 3;
      int sc = (ch & 7) ^ (row & 7);
      async16((char*)Bs + ch * 16,
              (const char*)W + ((size_t)(n0 + row) * K + kk * 64 + sc * 8) * 2);
    }
    __syncthreads();
#pragma unroll
    for (int kq = 0; kq < 2; kq++) {
      bf16x8_t a[4], b[4];
#pragma unroll
      for (int mt = 0; mt < 4; mt++) {
        int row = wm * 64 + mt * 16 + l15;
        int swz = (kq * 4 + quad) ^ (l15 & 7);
        a[mt] = *(const bf16x8_t*)(As + row * 64 + swz * 8);
      }
#pragma unroll
      for (int nt = 0; nt < 4; nt++) {
        int row = wn * 64 + nt * 16 + l15;
        int swz = (kq * 4 + quad) ^ (l15 & 7);
        b[nt] = *(const bf16x8_t*)(Bs + row * 64 + swz * 8);
      }
#pragma unroll
      for (int mt = 0; mt < 4; mt++)
#pragma unroll
        for (int nt = 0; nt < 4; nt++)
          acc[mt][nt] = __builtin_amdgcn_mfma_f32_16x16x32_bf16(a[mt], b[nt], acc[mt][nt], 0, 0, 0);
    }
  }

#pragma unroll
  for (int nt = 0; nt < 4; nt++) {
    int co = n0 + wn * 64 + nt * 16 + l15;
    float bv = bias[co];
#pragma unroll
    for (int mt = 0; mt < 4; mt++) {
#pragma unroll
      for (int r = 0; r < 4; r++) {
        int t = t0 + wm * 64 + mt * 16 + quad * 4 + r;
        float v = acc[mt][nt][r] + bv;
        if constexpr (EPI == 1) v = gelu_f(v);
        if constexpr (EPI >= 2) v += (float)res[(size_t)t * Co + co];
        if constexpr (EPI == 3) {
          int bb = t / NTOK, nsp = t % NTOK;
          outf[((size_t)bb * 384 + co) * NTOK + nsp] = v;
        } else {
          out[(size_t)t * Co + co] = bf16(v);
        }
      }
    }
  }
}

// ---------------- attention: one block per (b,h) — round-4 batch-P structure ----------------
__global__ __launch_bounds__(256) void attn_kernel(
    const bf16* __restrict__ q, int sq,
    const bf16* __restrict__ kv, int skv, int kofs0, int vofs0,
    const float* __restrict__ bmat, bf16* __restrict__ outp)
{
  __shared__ __align__(16) bf16 Ks[196 * 48];
  __shared__ __align__(16) bf16 VT[48 * 208];
  __shared__ __align__(16) bf16 Pl[4 * 16 * 208];
  const int b = blockIdx.x >> 3, h = blockIdx.x & 7;
  const int tid = threadIdx.x;
  const int lane = tid & 63, wv = tid >> 6;
  const int quad = lane >> 4, l15 = lane & 15;
  const int qoff = h * 48, koff = kofs0 + h * 48, voff = vofs0 + h * 48;
  const float SC = 0.14433756729740643f;  // 48^-0.5

  for (int j = 0; j < 5; j++) {
    int idx = j * 256 + tid;
    if (idx < 1176) {
      int o = idx * 16;
      int row = o / 96, colb = o % 96;
      async16((char*)Ks + o,
              (const char*)kv + ((size_t)(b * 196 + row) * skv + koff) * 2 + colb);
    }
  }
  for (int i = tid; i < 196 * 48; i += 256) {
    int mk = i / 48, d = i % 48;
    VT[d * 208 + mk] = kv[(size_t)(b * 196 + mk) * skv + voff + d];
  }
  for (int i = tid; i < 48 * 12; i += 256) {
    int d = i / 12, mk = 196 + (i % 12);
    VT[d * 208 + mk] = bf16(0.0f);
  }
  __syncthreads();

  bf16* Pw = Pl + wv * 16 * 208;

  for (int qt = wv; qt < 13; qt += 4) {
    int trow = qt * 16 + l15;
    int tl = trow < 196 ? trow : 195;
    const bf16* qrow = q + (size_t)(b * 196 + tl) * sq + qoff;
    bf16x8_t aq0 = *(const bf16x8_t*)(qrow + quad * 8);
    bf16x8_t aq1 = zero_bf16x8();
    if (quad < 2) aq1 = *(const bf16x8_t*)(qrow + 32 + quad * 8);

    f32x4_t S[13];
#pragma unroll
    for (int kt = 0; kt < 13; kt++) { S[kt][0] = 0.f; S[kt][1] = 0.f; S[kt][2] = 0.f; S[kt][3] = 0.f; }

#pragma unroll
    for (int kt = 0; kt < 13; kt++) {
      int kr = kt * 16 + l15;
      bf16x8_t bk0 = zero_bf16x8(), bk1 = zero_bf16x8();
      if (kr < 196) {
        const bf16* krow = Ks + kr * 48;
        bk0 = *(const bf16x8_t*)(krow + quad * 8);
        if (quad < 2) bk1 = *(const bf16x8_t*)(krow + 32 + quad * 8);
      }
      S[kt] = __builtin_amdgcn_mfma_f32_16x16x32_bf16(aq0, bk0, S[kt], 0, 0, 0);
      S[kt] = __builtin_amdgcn_mfma_f32_16x16x32_bf16(aq1, bk1, S[kt], 0, 0, 0);
    }

    float mrow[4] = {-1e30f, -1e30f, -1e30f, -1e30f};
#pragma unroll
    for (int kt = 0; kt < 13; kt++) {
      int m = kt * 16 + l15;
      int mc = m < 196 ? m : 195;
#pragma unroll
      for (int r = 0; r < 4; r++) {
        int qg = qt * 16 + quad * 4 + r;
        int qc = qg < 196 ? qg : 195;
        float s = S[kt][r] * SC + bmat[((size_t)h * 196 + qc) * 196 + mc];
        if (m >= 196) s = -1e30f;
        S[kt][r] = s;
        mrow[r] = fmaxf(mrow[r], s);
      }
    }
#pragma unroll
    for (int r = 0; r < 4; r++)
#pragma unroll
      for (int off = 1; off < 16; off <<= 1)
        mrow[r] = fmaxf(mrow[r], __shfl_xor(mrow[r], off));
    float srow[4] = {0.f, 0.f, 0.f, 0.f};
#pragma unroll
    for (int kt = 0; kt < 13; kt++)
#pragma unroll
      for (int r = 0; r < 4; r++) {
        float p = __expf(S[kt][r] - mrow[r]);
        S[kt][r] = p;
        srow[r] += p;
      }
#pragma unroll
    for (int r = 0; r < 4; r++) {
#pragma unroll
      for (int off = 1; off < 16; off <<= 1)
        srow[r] += __shfl_xor(srow[r], off);
      srow[r] = 1.0f / srow[r];
    }
#pragma unroll
    for (int kt = 0; kt < 13; kt++)
#pragma unroll
      for (int r = 0; r < 4; r++)
        Pw[(quad * 4 + r) * 208 + kt * 16 + l15] = bf16(S[kt][r] * srow[r]);

    f32x4_t O[3];
#pragma unroll
    for (int dt = 0; dt < 3; dt++) { O[dt][0] = 0.f; O[dt][1] = 0.f; O[dt][2] = 0.f; O[dt][3] = 0.f; }
#pragma unroll
    for (int ks = 0; ks < 7; ks++) {
      bool act = (ks < 6) || (quad < 2);
      bf16x8_t ap = zero_bf16x8();
      if (act) ap = *(const bf16x8_t*)(Pw + l15 * 208 + ks * 32 + quad * 8);
#pragma unroll
      for (int dt = 0; dt < 3; dt++) {
        bf16x8_t bv8 = zero_bf16x8();
        if (act) bv8 = *(const bf16x8_t*)(VT + (dt * 16 + l15) * 208 + ks * 32 + quad * 8);
        O[dt] = __builtin_amdgcn_mfma_f32_16x16x32_bf16(ap, bv8, O[dt], 0, 0, 0);
      }
    }
#pragma unroll
    for (int dt = 0; dt < 3; dt++)
#pragma unroll
      for (int r = 0; r < 4; r++) {
        int tq = qt * 16 + quad * 4 + r;
        if (tq < 196)
          outp[(size_t)(b * 196 + tq) * 384 + qoff + dt * 16 + l15] = bf16(O[dt][r]);
      }
  }
}

// ---------------- RepVGGDW (dw3x3 + dw1x1 + id) + GELU -> token-major bf16 ----------------
// v4: no LDS — direct global reads with a sliding 3-row register window.
__device__ __forceinline__ void load_row14(float* d, const float* rowp, bool valid) {
  if (valid) {
    const float2* p2 = (const float2*)rowp;
#pragma unroll
    for (int j = 0; j < 7; j++) { float2 v = p2[j]; d[2 * j] = v.x; d[2 * j + 1] = v.y; }
  } else {
#pragma unroll
    for (int w = 0; w < 14; w++) d[w] = 0.f;
  }
}

__global__ __launch_bounds__(256) void conv_kernel(
    const float* __restrict__ lh, const float* __restrict__ hl, const float* __restrict__ hh,
    const float* __restrict__ w3, const float* __restrict__ b3,
    const float* __restrict__ w1, const float* __restrict__ b1,
    bf16* __restrict__ outp)
{
  const int tid = threadIdx.x;
  const int b = blockIdx.x / 18, chunk = blockIdx.x % 18;
  const int c0 = chunk * 64;
  const float* src = (c0 < 384) ? lh : (c0 < 768 ? hl : hh);
  const int cc0 = c0 % 384;
  const int c = tid & 63;
  const int g = tid >> 6;               // band: rows 4g .. min(4g+3,13)
  const int cg = c0 + c;
  const float* base = src + ((size_t)b * 384 + cc0 + c) * 196;

  float w9[9];
#pragma unroll
  for (int k = 0; k < 9; k++) w9[k] = w3[cg * 9 + k];
  w9[4] += w1[cg] + 1.0f;               // fold dw1x1 + identity into center tap
  const float bb = b3[cg] + b1[cg];

  const int r0 = 4 * g;
  float rows[3][14];
  load_row14(rows[0], base + (r0 - 1) * 14, r0 - 1 >= 0);
  load_row14(rows[1], base + r0 * 14, true);

#pragma unroll
  for (int s = 0; s < 4; s++) {
    int r = r0 + s;
    if (r < 14) {
      float* rp = rows[(s + 2) % 3];
      load_row14(rp, base + (r + 1) * 14, r + 1 < 14);
      const float* rm = rows[s % 3];
      const float* rc = rows[(s + 1) % 3];
      bf16* orow = outp + ((size_t)b * 196 + r * 14) * 1152 + cg;
#pragma unroll
      for (int w = 0; w < 14; w++) {
        float ss = bb + rm[w] * w9[1] + rc[w] * w9[4] + rp[w] * w9[7];
        if (w > 0)  ss += rm[w - 1] * w9[0] + rc[w - 1] * w9[3] + rp[w - 1] * w9[6];
        if (w < 13) ss += rm[w + 1] * w9[2] + rc[w + 1] * w9[5] + rp[w + 1] * w9[8];
        orow[(size_t)w * 1152] = bf16(gelu_f(ss));
      }
    }
  }
}

// ---------------- SE: pool -> (scale matvec + apply fused) ----------------
__global__ __launch_bounds__(256) void pool_kernel(
    const float* __restrict__ ll, float* __restrict__ pooled)
{
  const int b = blockIdx.x / 6, chunk = blockIdx.x % 6;
  const int c0 = chunk * 64;
  const int wv = threadIdx.x >> 6, lane = threadIdx.x & 63;
  for (int c = wv; c < 64; c += 4) {
    const float* p = ll + ((size_t)b * 384 + c0 + c) * 196;
    float v = p[lane] + p[64 + lane] + p[128 + lane] + (lane < 4 ? p[192 + lane] : 0.f);
#pragma unroll
    for (int off = 32; off; off >>= 1) v += __shfl_xor(v, off);
    if (lane == 0) pooled[b * 384 + c0 + c] = v * (1.0f / 196.0f);
  }
}

__global__ __launch_bounds__(256) void seapply_kernel(
    const float* __restrict__ ll, const float* __restrict__ pooled,
    const float* __restrict__ ew, const float* __restrict__ eb,
    bf16* __restrict__ se)
{
  __shared__ float pl[384];
  __shared__ float scale[64];
  __shared__ float plane[64][197];
  const int tid = threadIdx.x;
  const int b = blockIdx.x / 6, chunk = blockIdx.x % 6;
  const int c0 = chunk * 64;
  const int wv = tid >> 6, lane = tid & 63;

  for (int i = tid; i < 384; i += 256) pl[i] = pooled[b * 384 + i];
  for (int i = tid; i < 64 * 196; i += 256) {
    int c = i / 196, n = i % 196;
    plane[c][n] = ll[((size_t)b * 384 + c0 + c) * 196 + n];
  }
  __syncthreads();
  for (int cc = wv; cc < 64; cc += 4) {
    const float* wr = ew + (size_t)(c0 + cc) * 384;
    float v = 0.f;
#pragma unroll
    for (int j = 0; j < 6; j++) v += wr[j * 64 + lane] * pl[j * 64 + lane];
#pragma unroll
    for (int off = 32; off; off >>= 1) v += __shfl_xor(v, off);
    if (lane == 0) {
      float y = (v + eb[c0 + cc]) * (1.0f / 6.0f) + 0.5f;
      scale[cc] = fminf(fmaxf(y, 0.f), 1.f);
    }
  }
  __syncthreads();
  const int c = tid & 63;
  const float sc = scale[c];
  for (int n = tid >> 6; n < 196; n += 4)
    se[((size_t)b * 196 + n) * 384 + c0 + c] = bf16(plane[c][n] * sc);
}

// ---------------- prep: weight f32->bf16 blob + bias-table materialize (merged) ----------------
__global__ __launch_bounds__(256) void prep_kernel(
    const float* p0, const float* p1, const float* p2, const float* p3, const float* p4,
    const float* p5, const float* p6, const float* p7, const float* p8, const float* p9,
    bf16* dst,
    const float* __restrict__ hbias, const float* __restrict__ lbias,
    const int* __restrict__ idx, float* __restrict__ bh, float* __restrict__ bl)
{
  const int bid = blockIdx.x;
  if (bid < 10944) {
    int i = bid * 256 + threadIdx.x;   // < 2801664 always
    const int offs[11] = {0, 442368, 884736, 1032192, 1327104, 1622016,
                          1769472, 2064384, 2211840, 2506752, 2801664};
    const float* ps[10] = {p0, p1, p2, p3, p4, p5, p6, p7, p8, p9};
    int seg = 0;
#pragma unroll
    for (int k = 1; k < 10; k++) if (i >= offs[k]) seg = k;
    dst[i] = bf16(ps[seg][i - offs[seg]]);
  } else {
    int i = (bid - 10944) * 256 + threadIdx.x;
    if (i >= 307328) return;  // 8 * 196 * 196
    int h = i / 38416;
    int nm = i % 38416;
    int id = idx[nm];
    bh[i] = hbias[h * 196 + id];
    bl[i] = lbias[h * 196 + id];
  }
}

extern "C" void kernel_launch(void* const* d_in, const int* in_sizes, int n_in,
                              void* d_out, int out_size, void* d_ws, size_t ws_size,
                              hipStream_t stream) {
  const float* ll     = (const float*)d_in[0];
  const float* lh     = (const float*)d_in[1];
  const float* hl     = (const float*)d_in[2];
  const float* hh     = (const float*)d_in[3];
  const float* dw3_w  = (const float*)d_in[4];
  const float* dw3_b  = (const float*)d_in[5];
  const float* dw1_w  = (const float*)d_in[6];
  const float* dw1_b  = (const float*)d_in[7];
  const float* pw_w   = (const float*)d_in[8];
  const float* pw_b   = (const float*)d_in[9];
  const float* hqkv_w = (const float*)d_in[10];
  const float* hqkv_b = (const float*)d_in[11];
  const float* hproj_w= (const float*)d_in[12];
  const float* hproj_b= (const float*)d_in[13];
  const float* hbias  = (const float*)d_in[14];
  const float* hm1_w  = (const float*)d_in[15];
  const float* hm1_b  = (const float*)d_in[16];
  const float* hm2_w  = (const float*)d_in[17];
  const float* hm2_b  = (const float*)d_in[18];
  const float* ese_w  = (const float*)d_in[19];
  const float* ese_b  = (const float*)d_in[20];
  const float* lq_w   = (const float*)d_in[21];
  const float* lq_b   = (const float*)d_in[22];
  const float* lkv_w  = (const float*)d_in[23];
  const float* lkv_b  = (const float*)d_in[24];
  const float* lproj_w= (const float*)d_in[25];
  const float* lproj_b= (const float*)d_in[26];
  const float* lbias  = (const float*)d_in[27];
  const float* lm1_w  = (const float*)d_in[28];
  const float* lm1_b  = (const float*)d_in[29];
  const float* lm2_w  = (const float*)d_in[30];
  const float* lm2_b  = (const float*)d_in[31];
  const int* bias_idx = (const int*)d_in[32];

  char* ws = (char*)d_ws;
  bf16*  WB = (bf16*)(ws);                    // 2801664 bf16 weights
  float* BH = (float*)(ws + 5603328);         // 8x196x196 f32
  float* BL = (float*)(ws + 6832640);
  bf16*  A  = (bf16*)(ws + 8061952);          // [T][1152]
  bf16*  B1 = (bf16*)(ws + 65864704);         // [T][384]
  bf16*  B2 = (bf16*)(ws + 85132288);         // [T][384]
  bf16*  B3 = (bf16*)(ws + 104399872);        // [T][384]
  bf16*  B4 = (bf16*)(ws + 123667456);        // [T][768]
  bf16*  E  = (bf16*)(ws + 162202624);        // [T][384] (se)
  float* PO = (float*)(ws + 181470208);       // pooled [128][384]
  float* OUT = (float*)d_out;

  prep_kernel<<<12145, 256, 0, stream>>>(pw_w, hqkv_w, hproj_w, hm1_w, hm2_w,
                                         lq_w, lkv_w, lproj_w, lm1_w, lm2_w, WB,
                                         hbias, lbias, bias_idx, BH, BL);
  conv_kernel<<<2304, 256, 0, stream>>>(lh, hl, hh, dw3_w, dw3_b, dw1_w, dw1_b, A);
  pool_kernel<<<768, 256, 0, stream>>>(ll, PO);
  seapply_kernel<<<768, 256, 0, stream>>>(ll, PO, ese_w, ese_b, E);

  // high branch
  gemm_bt<1152, 0, 64><<<dim3(392, 3), 128, 0, stream>>>(A, WB + 0, pw_b, nullptr, B1, nullptr, 384);         // hc
  gemm_bt<384, 0, 128><<<dim3(196, 9), 256, 0, stream>>>(B1, WB + 442368, hqkv_b, nullptr, A, nullptr, 1152); // qkv
  attn_kernel<<<1024, 256, 0, stream>>>(A, 1152, A, 1152, 384, 768, BH, B2);                                   // attn
  gemm_bt<384, 2, 64><<<dim3(392, 3), 128, 0, stream>>>(B2, WB + 884736, hproj_b, B1, B3, nullptr, 384);      // hao
  gemm_bt<384, 1, 128><<<dim3(196, 6), 256, 0, stream>>>(B3, WB + 1032192, hm1_b, nullptr, B4, nullptr, 768); // ffn1
  gemm_bt<768, 2, 64><<<dim3(392, 3), 128, 0, stream>>>(B4, WB + 1327104, hm2_b, B3, B1, nullptr, 384);       // refined

  // low branch
  gemm_bt<384, 0, 128><<<dim3(196, 6), 256, 0, stream>>>(B1, WB + 1769472, lkv_b, nullptr, B4, nullptr, 768); // lkv
  gemm_bt<384, 0, 64><<<dim3(392, 3), 128, 0, stream>>>(E, WB + 1622016, lq_b, nullptr, B2, nullptr, 384);    // lq
  attn_kernel<<<1024, 256, 0, stream>>>(B2, 384, B4, 768, 0, 384, BL, B1);                                     // low attn
  gemm_bt<384, 2, 64><<<dim3(392, 3), 128, 0, stream>>>(B1, WB + 2064384, lproj_b, E, B3, nullptr, 384);      // ll_attn
  gemm_bt<384, 1, 128><<<dim3(196, 6), 256, 0, stream>>>(B3, WB + 2211840, lm1_b, nullptr, A, nullptr, 768);  // ffn1
  gemm_bt<768, 3, 64><<<dim3(392, 3), 128, 0, stream>>>(A, WB + 2506752, lm2_b, B3, nullptr, OUT, 384);       // output
}